// Round 1
// baseline (9039.585 us; speedup 1.0000x reference)
//
#include <hip/hip_runtime.h>

#define BN_EPS 1e-5f

// ---------------- degree / norm ----------------
__global__ void k_deg(const int* __restrict__ dst, float* __restrict__ deg, int E) {
  int e = blockIdx.x * blockDim.x + threadIdx.x;
  if (e < E) atomicAdd(&deg[dst[e]], 1.0f);
}

__global__ void k_dinv(float* __restrict__ deg, int n) {
  int i = blockIdx.x * blockDim.x + threadIdx.x;
  if (i < n) deg[i] = rsqrtf(deg[i] + 1.0f);  // +1 self-loop; deg>=1 guaranteed
}

// ---------------- GEMM: Hout[n,128] = X[n,K] @ W[K,128] ----------------
// block = 256 threads = 2 half-blocks x 128 cols; each half-block does 4 rows.
// x reads are wave-uniform (scalarize), W reads coalesced.
__global__ void k_gemm(const float* __restrict__ X, const float* __restrict__ W,
                       float* __restrict__ Hout, int n, int K) {
  int col  = threadIdx.x & 127;
  int half = threadIdx.x >> 7;
  int row0 = blockIdx.x * 8 + half * 4;
  if (row0 >= n) return;
  if (row0 + 4 <= n) {
    const float* x0 = X + (size_t)row0 * K;
    float a0 = 0.f, a1 = 0.f, a2 = 0.f, a3 = 0.f;
    for (int k = 0; k < K; ++k) {
      float w = W[k * 128 + col];
      a0 = fmaf(x0[k],         w, a0);
      a1 = fmaf(x0[K + k],     w, a1);
      a2 = fmaf(x0[2 * K + k], w, a2);
      a3 = fmaf(x0[3 * K + k], w, a3);
    }
    size_t o = (size_t)row0 * 128 + col;
    Hout[o] = a0; Hout[o + 128] = a1; Hout[o + 256] = a2; Hout[o + 384] = a3;
  } else {
    for (int r = row0; r < n; ++r) {
      const float* xr = X + (size_t)r * K;
      float a = 0.f;
      for (int k = 0; k < K; ++k) a = fmaf(xr[k], W[k * 128 + col], a);
      Hout[(size_t)r * 128 + col] = a;
    }
  }
}

// ---------------- agg init: bias + self-loop contribution ----------------
__global__ void k_agginit(const float* __restrict__ h, const float* __restrict__ dinv,
                          const float* __restrict__ bias, float* __restrict__ agg, int n) {
  int idx = blockIdx.x * blockDim.x + threadIdx.x;  // over n*32 float4s
  if (idx >= n * 32) return;
  int row = idx >> 5, q = idx & 31;
  float di = dinv[row];
  float w = di * di;
  float4 hv = ((const float4*)h)[idx];
  float4 bv = ((const float4*)bias)[q];
  float4 r;
  r.x = fmaf(hv.x, w, bv.x);
  r.y = fmaf(hv.y, w, bv.y);
  r.z = fmaf(hv.z, w, bv.z);
  r.w = fmaf(hv.w, w, bv.w);
  ((float4*)agg)[idx] = r;
}

// ---------------- edge scatter: 32 lanes per edge, float4 gather + 4 atomics ----------------
__global__ void k_scatter(const int* __restrict__ src, const int* __restrict__ dst,
                          const float* __restrict__ dinv, const float* __restrict__ h,
                          float* __restrict__ agg, int E) {
  int t = blockIdx.x * blockDim.x + threadIdx.x;
  int e = t >> 5;
  if (e >= E) return;
  int lane = t & 31;
  int s = src[e], d = dst[e];
  float w = dinv[s] * dinv[d];
  float4 v = ((const float4*)(h + (size_t)s * 128))[lane];
  float* ad = agg + (size_t)d * 128 + lane * 4;
  atomicAdd(ad + 0, v.x * w);
  atomicAdd(ad + 1, v.y * w);
  atomicAdd(ad + 2, v.z * w);
  atomicAdd(ad + 3, v.w * w);
}

// ---------------- BN stats: per-column sum / sumsq ----------------
__global__ void k_bnstats(const float* __restrict__ a, float* __restrict__ bnsum, int n) {
  int col  = threadIdx.x & 127;
  int half = threadIdx.x >> 7;
  float s = 0.f, s2 = 0.f;
  for (int r = blockIdx.x * 2 + half; r < n; r += gridDim.x * 2) {
    float v = a[(size_t)r * 128 + col];
    s += v; s2 += v * v;
  }
  __shared__ float ls[256], ls2[256];
  ls[threadIdx.x] = s; ls2[threadIdx.x] = s2;
  __syncthreads();
  if (threadIdx.x < 128) {
    atomicAdd(&bnsum[col],       ls[threadIdx.x] + ls[threadIdx.x + 128]);
    atomicAdd(&bnsum[128 + col], ls2[threadIdx.x] + ls2[threadIdx.x + 128]);
  }
}

__global__ void k_bnfinal(const float* __restrict__ bnsum, const float* __restrict__ gamma,
                          const float* __restrict__ beta, float* __restrict__ scsh, int n) {
  int c = threadIdx.x;  // 128
  float invn = 1.0f / (float)n;
  float mu  = bnsum[c] * invn;
  float ex2 = bnsum[128 + c] * invn;
  float var = fmaxf(ex2 - mu * mu, 0.f);
  float sc = gamma[c] * rsqrtf(var + BN_EPS);
  scsh[c] = sc;
  scsh[128 + c] = fmaf(-mu, sc, beta[c]);
}

// ---------------- BN apply + ReLU (in place) ----------------
__global__ void k_bnapply(float* __restrict__ a, const float* __restrict__ scsh, int n) {
  int idx = blockIdx.x * blockDim.x + threadIdx.x;  // over n*32 float4s
  if (idx >= n * 32) return;
  int q = idx & 31;
  float4 v  = ((float4*)a)[idx];
  float4 sc = ((const float4*)scsh)[q];
  float4 sh = ((const float4*)(scsh + 128))[q];
  v.x = fmaxf(fmaf(v.x, sc.x, sh.x), 0.f);
  v.y = fmaxf(fmaf(v.y, sc.y, sh.y), 0.f);
  v.z = fmaxf(fmaf(v.z, sc.z, sh.z), 0.f);
  v.w = fmaxf(fmaf(v.w, sc.w, sh.w), 0.f);
  ((float4*)a)[idx] = v;
}

// ---------------- graph boundaries via binary search (batch sorted) ----------------
__global__ void k_gstart(const int* __restrict__ batch, int* __restrict__ gstart, int n, int G) {
  int g = blockIdx.x * blockDim.x + threadIdx.x;
  if (g > G) return;
  int lo = 0, hi = n;
  while (lo < hi) {
    int mid = (lo + hi) >> 1;
    if (batch[mid] < g) lo = mid + 1; else hi = mid;
  }
  gstart[g] = lo;
}

// ---------------- mean pool: one block per graph ----------------
__global__ void k_pool(const float* __restrict__ x, const int* __restrict__ gstart,
                       float* __restrict__ pooled) {
  int g = blockIdx.x, c = threadIdx.x;  // 128 threads
  int s = gstart[g], e = gstart[g + 1];
  float acc = 0.f;
  for (int i = s; i < e; ++i) acc += x[(size_t)i * 128 + c];
  float cnt = (float)(e - s);
  pooled[(size_t)g * 128 + c] = acc / fmaxf(cnt, 1.f);
}

// ---------------- head MLP: one wave per graph ----------------
__global__ void k_head(const float* __restrict__ pooled, const float* __restrict__ HW1,
                       const float* __restrict__ Hb1, const float* __restrict__ HW2,
                       const float* __restrict__ Hb2, float* __restrict__ out) {
  int g = blockIdx.x, j = threadIdx.x;  // 64 threads
  __shared__ float p[128];
  p[j]      = pooled[(size_t)g * 128 + j];
  p[j + 64] = pooled[(size_t)g * 128 + 64 + j];
  __syncthreads();
  float acc = Hb1[j];
  for (int k = 0; k < 128; ++k) acc = fmaf(p[k], HW1[k * 64 + j], acc);
  float v = fmaxf(acc, 0.f) * HW2[j];
  for (int off = 32; off > 0; off >>= 1) v += __shfl_down(v, off);
  if (j == 0) out[g] = v + Hb2[0];
}

extern "C" void kernel_launch(void* const* d_in, const int* in_sizes, int n_in,
                              void* d_out, int out_size, void* d_ws, size_t ws_size,
                              hipStream_t stream) {
  const int F_IN = 30, H = 128;
  const float* x   = (const float*)d_in[0];
  const int* eidx  = (const int*)d_in[1];
  const int* batch = (const int*)d_in[2];
  const int N = in_sizes[0] / F_IN;
  const int E = in_sizes[1] / 2;
  const int G = out_size;
  const int* srcp = eidx;
  const int* dstp = eidx + E;
  const float* HW1 = (const float*)d_in[15];
  const float* Hb1 = (const float*)d_in[16];
  const float* HW2 = (const float*)d_in[17];
  const float* Hb2 = (const float*)d_in[18];
  float* outp = (float*)d_out;

  // workspace layout (floats)
  float* ws   = (float*)d_ws;
  size_t nh   = (size_t)N * H;
  float* bufH = ws;              // N*128  (gemm output h)
  float* bufX = bufH + nh;       // N*128  (agg, then BN output / next layer input)
  float* dinv = bufX + nh;       // N (padded to 100096)
  float* bnsum  = dinv + 100096; // 256
  float* scsh   = bnsum + 256;   // 256
  float* pooled = scsh + 256;    // G*128
  int*   gstart = (int*)(pooled + (size_t)G * 128);  // G+1

  // degree -> dinv
  hipMemsetAsync(dinv, 0, (size_t)N * sizeof(float), stream);
  k_deg<<<(E + 255) / 256, 256, 0, stream>>>(dstp, dinv, E);
  k_dinv<<<(N + 255) / 256, 256, 0, stream>>>(dinv, N);

  const float* xin = x;
  int K = F_IN;
  for (int l = 0; l < 3; ++l) {
    const float* W  = (const float*)d_in[3 + l * 4];
    const float* b  = (const float*)d_in[4 + l * 4];
    const float* gm = (const float*)d_in[5 + l * 4];
    const float* bt = (const float*)d_in[6 + l * 4];

    k_gemm<<<(N + 7) / 8, 256, 0, stream>>>(xin, W, bufH, N, K);
    k_agginit<<<(N * 32 + 255) / 256, 256, 0, stream>>>(bufH, dinv, b, bufX, N);
    k_scatter<<<(int)(((size_t)E * 32 + 255) / 256), 256, 0, stream>>>(srcp, dstp, dinv, bufH, bufX, E);
    hipMemsetAsync(bnsum, 0, 256 * sizeof(float), stream);
    k_bnstats<<<512, 256, 0, stream>>>(bufX, bnsum, N);
    k_bnfinal<<<1, 128, 0, stream>>>(bnsum, gm, bt, scsh, N);
    k_bnapply<<<(N * 32 + 255) / 256, 256, 0, stream>>>(bufX, scsh, N);

    xin = bufX;
    K = H;
  }

  // pooling + head
  k_gstart<<<3, 256, 0, stream>>>(batch, gstart, N, G);
  k_pool<<<G, 128, 0, stream>>>(bufX, gstart, pooled);
  k_head<<<G, 64, 0, stream>>>(pooled, HW1, Hb1, HW2, Hb2, outp);
}

// Round 2
// 1912.253 us; speedup vs baseline: 4.7272x; 4.7272x over previous
//
#include <hip/hip_runtime.h>

#define BN_EPS 1e-5f

// ---------------- indegree count (int) ----------------
__global__ void k_count(const int* __restrict__ dst, int* __restrict__ cnt, int E) {
  int e = blockIdx.x * blockDim.x + threadIdx.x;
  if (e < E) atomicAdd(&cnt[dst[e]], 1);
}

// dinv[i] = rsqrt(indeg + 1)   (+1 = self-loop)
__global__ void k_dinv(const int* __restrict__ cnt, float* __restrict__ dinv, int n) {
  int i = blockIdx.x * blockDim.x + threadIdx.x;
  if (i < n) dinv[i] = rsqrtf((float)cnt[i] + 1.0f);
}

// allocate a contiguous chunk per dst (segment order irrelevant -> no scan needed)
__global__ void k_alloc(const int* __restrict__ cnt, int* __restrict__ start,
                        int* __restrict__ cursor, int* __restrict__ total, int n) {
  int i = blockIdx.x * blockDim.x + threadIdx.x;
  if (i < n) {
    int c = cnt[i];
    int p = atomicAdd(total, c);
    start[i] = p;
    cursor[i] = p;
  }
}

// place (src, weight) pairs into per-dst chunks
__global__ void k_place(const int* __restrict__ src, const int* __restrict__ dst,
                        const float* __restrict__ dinv, int* __restrict__ cursor,
                        int2* __restrict__ elist, int E) {
  int e = blockIdx.x * blockDim.x + threadIdx.x;
  if (e >= E) return;
  int s = src[e], d = dst[e];
  int pos = atomicAdd(&cursor[d], 1);
  int2 v;
  v.x = s;
  v.y = __float_as_int(dinv[s] * dinv[d]);
  elist[pos] = v;
}

// ---------------- GEMM: Hout[n,128] = X[n,K] @ W[K,128] ----------------
__global__ void k_gemm(const float* __restrict__ X, const float* __restrict__ W,
                       float* __restrict__ Hout, int n, int K) {
  int col  = threadIdx.x & 127;
  int half = threadIdx.x >> 7;
  int row0 = blockIdx.x * 8 + half * 4;
  if (row0 >= n) return;
  if (row0 + 4 <= n) {
    const float* x0 = X + (size_t)row0 * K;
    float a0 = 0.f, a1 = 0.f, a2 = 0.f, a3 = 0.f;
    for (int k = 0; k < K; ++k) {
      float w = W[k * 128 + col];
      a0 = fmaf(x0[k],         w, a0);
      a1 = fmaf(x0[K + k],     w, a1);
      a2 = fmaf(x0[2 * K + k], w, a2);
      a3 = fmaf(x0[3 * K + k], w, a3);
    }
    size_t o = (size_t)row0 * 128 + col;
    Hout[o] = a0; Hout[o + 128] = a1; Hout[o + 256] = a2; Hout[o + 384] = a3;
  } else {
    for (int r = row0; r < n; ++r) {
      const float* xr = X + (size_t)r * K;
      float a = 0.f;
      for (int k = 0; k < K; ++k) a = fmaf(xr[k], W[k * 128 + col], a);
      Hout[(size_t)r * 128 + col] = a;
    }
  }
}

// ---------------- CSR gather: agg[d] = b + h[d]*dinv[d]^2 + sum w*h[src] ----------------
// 256 threads = 2 rows x 128 cols
__global__ void k_gather(const int2* __restrict__ elist, const int* __restrict__ start,
                         const int* __restrict__ cnt, const float* __restrict__ dinv,
                         const float* __restrict__ h, const float* __restrict__ bias,
                         float* __restrict__ agg, int n) {
  int col = threadIdx.x & 127;
  int row = blockIdx.x * 2 + (threadIdx.x >> 7);
  if (row >= n) return;
  float di = dinv[row];
  float acc = fmaf(h[(size_t)row * 128 + col], di * di, bias[col]);
  int s0 = start[row], len = cnt[row];
  const int2* ep = elist + s0;
  for (int j = 0; j < len; ++j) {
    int2 e = ep[j];
    acc = fmaf(h[(size_t)e.x * 128 + col], __int_as_float(e.y), acc);
  }
  agg[(size_t)row * 128 + col] = acc;
}

// ---------------- BN stats: per-column sum / sumsq ----------------
__global__ void k_bnstats(const float* __restrict__ a, float* __restrict__ bnsum, int n) {
  int col  = threadIdx.x & 127;
  int half = threadIdx.x >> 7;
  float s = 0.f, s2 = 0.f;
  for (int r = blockIdx.x * 2 + half; r < n; r += gridDim.x * 2) {
    float v = a[(size_t)r * 128 + col];
    s += v; s2 += v * v;
  }
  __shared__ float ls[256], ls2[256];
  ls[threadIdx.x] = s; ls2[threadIdx.x] = s2;
  __syncthreads();
  if (threadIdx.x < 128) {
    atomicAdd(&bnsum[col],       ls[threadIdx.x] + ls[threadIdx.x + 128]);
    atomicAdd(&bnsum[128 + col], ls2[threadIdx.x] + ls2[threadIdx.x + 128]);
  }
}

__global__ void k_bnfinal(const float* __restrict__ bnsum, const float* __restrict__ gamma,
                          const float* __restrict__ beta, float* __restrict__ scsh, int n) {
  int c = threadIdx.x;  // 128
  float invn = 1.0f / (float)n;
  float mu  = bnsum[c] * invn;
  float ex2 = bnsum[128 + c] * invn;
  float var = fmaxf(ex2 - mu * mu, 0.f);
  float sc = gamma[c] * rsqrtf(var + BN_EPS);
  scsh[c] = sc;
  scsh[128 + c] = fmaf(-mu, sc, beta[c]);
}

// ---------------- BN apply + ReLU (in place) ----------------
__global__ void k_bnapply(float* __restrict__ a, const float* __restrict__ scsh, int n) {
  int idx = blockIdx.x * blockDim.x + threadIdx.x;  // over n*32 float4s
  if (idx >= n * 32) return;
  int q = idx & 31;
  float4 v  = ((float4*)a)[idx];
  float4 sc = ((const float4*)scsh)[q];
  float4 sh = ((const float4*)(scsh + 128))[q];
  v.x = fmaxf(fmaf(v.x, sc.x, sh.x), 0.f);
  v.y = fmaxf(fmaf(v.y, sc.y, sh.y), 0.f);
  v.z = fmaxf(fmaf(v.z, sc.z, sh.z), 0.f);
  v.w = fmaxf(fmaf(v.w, sc.w, sh.w), 0.f);
  ((float4*)a)[idx] = v;
}

// ---------------- graph boundaries via binary search (batch sorted) ----------------
__global__ void k_gstart(const int* __restrict__ batch, int* __restrict__ gstart, int n, int G) {
  int g = blockIdx.x * blockDim.x + threadIdx.x;
  if (g > G) return;
  int lo = 0, hi = n;
  while (lo < hi) {
    int mid = (lo + hi) >> 1;
    if (batch[mid] < g) lo = mid + 1; else hi = mid;
  }
  gstart[g] = lo;
}

// ---------------- mean pool: one block per graph ----------------
__global__ void k_pool(const float* __restrict__ x, const int* __restrict__ gstart,
                       float* __restrict__ pooled) {
  int g = blockIdx.x, c = threadIdx.x;  // 128 threads
  int s = gstart[g], e = gstart[g + 1];
  float acc = 0.f;
  for (int i = s; i < e; ++i) acc += x[(size_t)i * 128 + c];
  float cnt = (float)(e - s);
  pooled[(size_t)g * 128 + c] = acc / fmaxf(cnt, 1.f);
}

// ---------------- head MLP: one wave per graph ----------------
__global__ void k_head(const float* __restrict__ pooled, const float* __restrict__ HW1,
                       const float* __restrict__ Hb1, const float* __restrict__ HW2,
                       const float* __restrict__ Hb2, float* __restrict__ out) {
  int g = blockIdx.x, j = threadIdx.x;  // 64 threads
  __shared__ float p[128];
  p[j]      = pooled[(size_t)g * 128 + j];
  p[j + 64] = pooled[(size_t)g * 128 + 64 + j];
  __syncthreads();
  float acc = Hb1[j];
  for (int k = 0; k < 128; ++k) acc = fmaf(p[k], HW1[k * 64 + j], acc);
  float v = fmaxf(acc, 0.f) * HW2[j];
  for (int off = 32; off > 0; off >>= 1) v += __shfl_down(v, off);
  if (j == 0) out[g] = v + Hb2[0];
}

extern "C" void kernel_launch(void* const* d_in, const int* in_sizes, int n_in,
                              void* d_out, int out_size, void* d_ws, size_t ws_size,
                              hipStream_t stream) {
  const int F_IN = 30, H = 128;
  const float* x   = (const float*)d_in[0];
  const int* eidx  = (const int*)d_in[1];
  const int* batch = (const int*)d_in[2];
  const int N = in_sizes[0] / F_IN;
  const int E = in_sizes[1] / 2;
  const int G = out_size;
  const int* srcp = eidx;
  const int* dstp = eidx + E;
  const float* HW1 = (const float*)d_in[15];
  const float* Hb1 = (const float*)d_in[16];
  const float* HW2 = (const float*)d_in[17];
  const float* Hb2 = (const float*)d_in[18];
  float* outp = (float*)d_out;

  // workspace layout
  float* ws   = (float*)d_ws;
  size_t nh   = (size_t)N * H;
  float* bufH = ws;              // N*128  (gemm output h)
  float* bufX = bufH + nh;       // N*128  (agg / BN output / next layer input)
  float* dinv = bufX + nh;       // N
  int*   cnt    = (int*)(dinv + N);     // N
  int*   startv = cnt + N;              // N
  int*   cursor = startv + N;           // N
  int*   total  = cursor + N;           // 64 (pad)
  float* bnsum  = (float*)(total + 64); // 256
  float* scsh   = bnsum + 256;          // 256
  float* pooled = scsh + 256;           // G*128
  int*   gstart = (int*)(pooled + (size_t)G * 128);  // G+1
  int2*  elist  = (int2*)(gstart + G + 64);          // E pairs

  // ---- build CSR (once, reused by all 3 layers) ----
  hipMemsetAsync(cnt, 0, (size_t)N * sizeof(int), stream);
  hipMemsetAsync(total, 0, sizeof(int), stream);
  k_count<<<(E + 255) / 256, 256, 0, stream>>>(dstp, cnt, E);
  k_dinv<<<(N + 255) / 256, 256, 0, stream>>>(cnt, dinv, N);
  k_alloc<<<(N + 255) / 256, 256, 0, stream>>>(cnt, startv, cursor, total, N);
  k_place<<<(E + 255) / 256, 256, 0, stream>>>(srcp, dstp, dinv, cursor, elist, E);

  const float* xin = x;
  int K = F_IN;
  for (int l = 0; l < 3; ++l) {
    const float* W  = (const float*)d_in[3 + l * 4];
    const float* b  = (const float*)d_in[4 + l * 4];
    const float* gm = (const float*)d_in[5 + l * 4];
    const float* bt = (const float*)d_in[6 + l * 4];

    k_gemm<<<(N + 7) / 8, 256, 0, stream>>>(xin, W, bufH, N, K);
    k_gather<<<(N + 1) / 2, 256, 0, stream>>>(elist, startv, cnt, dinv, bufH, b, bufX, N);
    hipMemsetAsync(bnsum, 0, 256 * sizeof(float), stream);
    k_bnstats<<<512, 256, 0, stream>>>(bufX, bnsum, N);
    k_bnfinal<<<1, 128, 0, stream>>>(bnsum, gm, bt, scsh, N);
    k_bnapply<<<(N * 32 + 255) / 256, 256, 0, stream>>>(bufX, scsh, N);

    xin = bufX;
    K = H;
  }

  // pooling + head
  k_gstart<<<3, 256, 0, stream>>>(batch, gstart, N, G);
  k_pool<<<G, 128, 0, stream>>>(bufX, gstart, pooled);
  k_head<<<G, 64, 0, stream>>>(pooled, HW1, Hb1, HW2, Hb2, outp);
}

// Round 3
// 1253.957 us; speedup vs baseline: 7.2089x; 1.5250x over previous
//
#include <hip/hip_runtime.h>

#define BN_EPS 1e-5f

__device__ inline float bf2f(unsigned int bits16) {
  return __uint_as_float(bits16 << 16);
}
__device__ inline unsigned short f2bf(float f) {
  unsigned int u = __float_as_uint(f);
  u += 0x7FFFu + ((u >> 16) & 1u);  // RNE
  return (unsigned short)(u >> 16);
}

// ---------------- indegree count (int) ----------------
__global__ void k_count(const int* __restrict__ dst, int* __restrict__ cnt, int E) {
  int e = blockIdx.x * blockDim.x + threadIdx.x;
  if (e < E) atomicAdd(&cnt[dst[e]], 1);
}

__global__ void k_dinv(const int* __restrict__ cnt, float* __restrict__ dinv, int n) {
  int i = blockIdx.x * blockDim.x + threadIdx.x;
  if (i < n) dinv[i] = rsqrtf((float)cnt[i] + 1.0f);
}

__global__ void k_alloc(const int* __restrict__ cnt, int* __restrict__ start,
                        int* __restrict__ cursor, int* __restrict__ total, int n) {
  int i = blockIdx.x * blockDim.x + threadIdx.x;
  if (i < n) {
    int c = cnt[i];
    int p = atomicAdd(total, c);
    start[i] = p;
    cursor[i] = p;
  }
}

__global__ void k_place(const int* __restrict__ src, const int* __restrict__ dst,
                        const float* __restrict__ dinv, int* __restrict__ cursor,
                        int2* __restrict__ elist, int E) {
  int e = blockIdx.x * blockDim.x + threadIdx.x;
  if (e >= E) return;
  int s = src[e], d = dst[e];
  int pos = atomicAdd(&cursor[d], 1);
  int2 v;
  v.x = s;
  v.y = __float_as_int(dinv[s] * dinv[d]);
  elist[pos] = v;
}

// ---------------- GEMM: Hout[n,128](bf16) = X[n,K](f32) @ W[K,128] ----------------
__global__ void k_gemm(const float* __restrict__ X, const float* __restrict__ W,
                       unsigned short* __restrict__ Hout, int n, int K) {
  int col  = threadIdx.x & 127;
  int half = threadIdx.x >> 7;
  int row0 = blockIdx.x * 8 + half * 4;
  if (row0 >= n) return;
  if (row0 + 4 <= n) {
    const float* x0 = X + (size_t)row0 * K;
    float a0 = 0.f, a1 = 0.f, a2 = 0.f, a3 = 0.f;
    for (int k = 0; k < K; ++k) {
      float w = W[k * 128 + col];
      a0 = fmaf(x0[k],         w, a0);
      a1 = fmaf(x0[K + k],     w, a1);
      a2 = fmaf(x0[2 * K + k], w, a2);
      a3 = fmaf(x0[3 * K + k], w, a3);
    }
    size_t o = (size_t)row0 * 128 + col;
    Hout[o] = f2bf(a0); Hout[o + 128] = f2bf(a1);
    Hout[o + 256] = f2bf(a2); Hout[o + 384] = f2bf(a3);
  } else {
    for (int r = row0; r < n; ++r) {
      const float* xr = X + (size_t)r * K;
      float a = 0.f;
      for (int k = 0; k < K; ++k) a = fmaf(xr[k], W[k * 128 + col], a);
      Hout[(size_t)r * 128 + col] = f2bf(a);
    }
  }
}

// ---------------- CSR gather (bf16 h, 2 cols/thread, 4-edge unroll) ----------------
// block 256 = 4 rows x 64 threads; thread t handles cols {2t, 2t+1} via dword load.
__global__ void k_gather(const int2* __restrict__ elist, const int* __restrict__ start,
                         const int* __restrict__ cnt, const float* __restrict__ dinv,
                         const unsigned int* __restrict__ h,  // bf16x2, row stride 64 dwords
                         const float* __restrict__ bias, float* __restrict__ agg, int n) {
  int t   = threadIdx.x & 63;
  int row = blockIdx.x * 4 + (threadIdx.x >> 6);
  if (row >= n) return;
  float di = dinv[row];
  float w0 = di * di;
  float2 bv = ((const float2*)bias)[t];
  unsigned int hv = h[(size_t)row * 64 + t];
  float acc0 = fmaf(bf2f(hv & 0xFFFFu), w0, bv.x);
  float acc1 = fmaf(bf2f(hv >> 16),     w0, bv.y);
  int s0 = start[row], len = cnt[row];
  const int2* ep = elist + s0;
  int j = 0;
  for (; j + 4 <= len; j += 4) {
    int2 e0 = ep[j], e1 = ep[j + 1], e2 = ep[j + 2], e3 = ep[j + 3];
    unsigned int v0 = h[(size_t)e0.x * 64 + t];
    unsigned int v1 = h[(size_t)e1.x * 64 + t];
    unsigned int v2 = h[(size_t)e2.x * 64 + t];
    unsigned int v3 = h[(size_t)e3.x * 64 + t];
    float w0f = __int_as_float(e0.y), w1f = __int_as_float(e1.y);
    float w2f = __int_as_float(e2.y), w3f = __int_as_float(e3.y);
    acc0 = fmaf(bf2f(v0 & 0xFFFFu), w0f, acc0);
    acc1 = fmaf(bf2f(v0 >> 16),     w0f, acc1);
    acc0 = fmaf(bf2f(v1 & 0xFFFFu), w1f, acc0);
    acc1 = fmaf(bf2f(v1 >> 16),     w1f, acc1);
    acc0 = fmaf(bf2f(v2 & 0xFFFFu), w2f, acc0);
    acc1 = fmaf(bf2f(v2 >> 16),     w2f, acc1);
    acc0 = fmaf(bf2f(v3 & 0xFFFFu), w3f, acc0);
    acc1 = fmaf(bf2f(v3 >> 16),     w3f, acc1);
  }
  for (; j < len; ++j) {
    int2 e = ep[j];
    unsigned int v = h[(size_t)e.x * 64 + t];
    float wf = __int_as_float(e.y);
    acc0 = fmaf(bf2f(v & 0xFFFFu), wf, acc0);
    acc1 = fmaf(bf2f(v >> 16),     wf, acc1);
  }
  float2 r; r.x = acc0; r.y = acc1;
  ((float2*)agg)[(size_t)row * 64 + t] = r;
}

// ---------------- BN stats: per-column sum / sumsq ----------------
__global__ void k_bnstats(const float* __restrict__ a, float* __restrict__ bnsum, int n) {
  int col  = threadIdx.x & 127;
  int half = threadIdx.x >> 7;
  float s = 0.f, s2 = 0.f;
  for (int r = blockIdx.x * 2 + half; r < n; r += gridDim.x * 2) {
    float v = a[(size_t)r * 128 + col];
    s += v; s2 += v * v;
  }
  __shared__ float ls[256], ls2[256];
  ls[threadIdx.x] = s; ls2[threadIdx.x] = s2;
  __syncthreads();
  if (threadIdx.x < 128) {
    atomicAdd(&bnsum[col],       ls[threadIdx.x] + ls[threadIdx.x + 128]);
    atomicAdd(&bnsum[128 + col], ls2[threadIdx.x] + ls2[threadIdx.x + 128]);
  }
}

__global__ void k_bnfinal(const float* __restrict__ bnsum, const float* __restrict__ gamma,
                          const float* __restrict__ beta, float* __restrict__ scsh, int n) {
  int c = threadIdx.x;  // 128
  float invn = 1.0f / (float)n;
  float mu  = bnsum[c] * invn;
  float ex2 = bnsum[128 + c] * invn;
  float var = fmaxf(ex2 - mu * mu, 0.f);
  float sc = gamma[c] * rsqrtf(var + BN_EPS);
  scsh[c] = sc;
  scsh[128 + c] = fmaf(-mu, sc, beta[c]);
}

// ---------------- BN apply + ReLU (in place) ----------------
__global__ void k_bnapply(float* __restrict__ a, const float* __restrict__ scsh, int n) {
  int idx = blockIdx.x * blockDim.x + threadIdx.x;  // over n*32 float4s
  if (idx >= n * 32) return;
  int q = idx & 31;
  float4 v  = ((float4*)a)[idx];
  float4 sc = ((const float4*)scsh)[q];
  float4 sh = ((const float4*)(scsh + 128))[q];
  v.x = fmaxf(fmaf(v.x, sc.x, sh.x), 0.f);
  v.y = fmaxf(fmaf(v.y, sc.y, sh.y), 0.f);
  v.z = fmaxf(fmaf(v.z, sc.z, sh.z), 0.f);
  v.w = fmaxf(fmaf(v.w, sc.w, sh.w), 0.f);
  ((float4*)a)[idx] = v;
}

// ---------------- graph boundaries via binary search (batch sorted) ----------------
__global__ void k_gstart(const int* __restrict__ batch, int* __restrict__ gstart, int n, int G) {
  int g = blockIdx.x * blockDim.x + threadIdx.x;
  if (g > G) return;
  int lo = 0, hi = n;
  while (lo < hi) {
    int mid = (lo + hi) >> 1;
    if (batch[mid] < g) lo = mid + 1; else hi = mid;
  }
  gstart[g] = lo;
}

// ---------------- mean pool over raw agg, fusing final BN+ReLU ----------------
__global__ void k_pool(const float* __restrict__ a, const float* __restrict__ scsh,
                       const int* __restrict__ gstart, float* __restrict__ pooled) {
  int g = blockIdx.x, c = threadIdx.x;  // 128 threads
  int s = gstart[g], e = gstart[g + 1];
  float sc = scsh[c], sh = scsh[128 + c];
  float acc = 0.f;
  for (int i = s; i < e; ++i)
    acc += fmaxf(fmaf(a[(size_t)i * 128 + c], sc, sh), 0.f);
  float cntf = (float)(e - s);
  pooled[(size_t)g * 128 + c] = acc / fmaxf(cntf, 1.f);
}

// ---------------- head MLP: one wave per graph ----------------
__global__ void k_head(const float* __restrict__ pooled, const float* __restrict__ HW1,
                       const float* __restrict__ Hb1, const float* __restrict__ HW2,
                       const float* __restrict__ Hb2, float* __restrict__ out) {
  int g = blockIdx.x, j = threadIdx.x;  // 64 threads
  __shared__ float p[128];
  p[j]      = pooled[(size_t)g * 128 + j];
  p[j + 64] = pooled[(size_t)g * 128 + 64 + j];
  __syncthreads();
  float acc = Hb1[j];
  for (int k = 0; k < 128; ++k) acc = fmaf(p[k], HW1[k * 64 + j], acc);
  float v = fmaxf(acc, 0.f) * HW2[j];
  for (int off = 32; off > 0; off >>= 1) v += __shfl_down(v, off);
  if (j == 0) out[g] = v + Hb2[0];
}

extern "C" void kernel_launch(void* const* d_in, const int* in_sizes, int n_in,
                              void* d_out, int out_size, void* d_ws, size_t ws_size,
                              hipStream_t stream) {
  const int F_IN = 30, H = 128;
  const float* x   = (const float*)d_in[0];
  const int* eidx  = (const int*)d_in[1];
  const int* batch = (const int*)d_in[2];
  const int N = in_sizes[0] / F_IN;
  const int E = in_sizes[1] / 2;
  const int G = out_size;
  const int* srcp = eidx;
  const int* dstp = eidx + E;
  const float* HW1 = (const float*)d_in[15];
  const float* Hb1 = (const float*)d_in[16];
  const float* HW2 = (const float*)d_in[17];
  const float* Hb2 = (const float*)d_in[18];
  float* outp = (float*)d_out;

  // workspace layout
  float* ws   = (float*)d_ws;
  size_t nh   = (size_t)N * H;
  unsigned short* bufH = (unsigned short*)ws;   // N*128 bf16 (gemm output h)
  float* bufX = ws + nh;         // N*128 f32 (agg / BN output / next layer input)
  float* dinv = bufX + nh;       // N
  int*   cnt    = (int*)(dinv + N);     // N
  int*   startv = cnt + N;              // N
  int*   cursor = startv + N;           // N
  int*   total  = cursor + N;           // 64 (pad)
  float* bnsum  = (float*)(total + 64); // 256
  float* scsh   = bnsum + 256;          // 256
  float* pooled = scsh + 256;           // G*128
  int*   gstart = (int*)(pooled + (size_t)G * 128);  // G+1
  int2*  elist  = (int2*)(gstart + G + 64);          // E pairs

  // ---- build CSR (once, reused by all 3 layers) ----
  hipMemsetAsync(cnt, 0, (size_t)N * sizeof(int), stream);
  hipMemsetAsync(total, 0, sizeof(int), stream);
  k_count<<<(E + 255) / 256, 256, 0, stream>>>(dstp, cnt, E);
  k_dinv<<<(N + 255) / 256, 256, 0, stream>>>(cnt, dinv, N);
  k_alloc<<<(N + 255) / 256, 256, 0, stream>>>(cnt, startv, cursor, total, N);
  k_place<<<(E + 255) / 256, 256, 0, stream>>>(srcp, dstp, dinv, cursor, elist, E);

  const float* xin = x;
  int K = F_IN;
  for (int l = 0; l < 3; ++l) {
    const float* W  = (const float*)d_in[3 + l * 4];
    const float* b  = (const float*)d_in[4 + l * 4];
    const float* gm = (const float*)d_in[5 + l * 4];
    const float* bt = (const float*)d_in[6 + l * 4];

    k_gemm<<<(N + 7) / 8, 256, 0, stream>>>(xin, W, bufH, N, K);
    k_gather<<<(N + 3) / 4, 256, 0, stream>>>(elist, startv, cnt, dinv,
                                              (const unsigned int*)bufH, b, bufX, N);
    hipMemsetAsync(bnsum, 0, 256 * sizeof(float), stream);
    k_bnstats<<<512, 256, 0, stream>>>(bufX, bnsum, N);
    k_bnfinal<<<1, 128, 0, stream>>>(bnsum, gm, bt, scsh, N);
    if (l < 2)  // last layer's BN+ReLU is fused into k_pool
      k_bnapply<<<(N * 32 + 255) / 256, 256, 0, stream>>>(bufX, scsh, N);

    xin = bufX;
    K = H;
  }

  // pooling (applies layer-2 BN+ReLU) + head
  k_gstart<<<3, 256, 0, stream>>>(batch, gstart, N, G);
  k_pool<<<G, 128, 0, stream>>>(bufX, scsh, gstart, pooled);
  k_head<<<G, 64, 0, stream>>>(pooled, HW1, Hb1, HW2, Hb2, outp);
}

// Round 4
// 800.162 us; speedup vs baseline: 11.2972x; 1.5671x over previous
//
#include <hip/hip_runtime.h>

#define BN_EPS 1e-5f

typedef __attribute__((ext_vector_type(8))) short bf16x8;
typedef __attribute__((ext_vector_type(4))) float f32x4;

__device__ inline float bf2f(unsigned int bits16) {
  return __uint_as_float(bits16 << 16);
}
__device__ inline unsigned short f2bf(float f) {
  unsigned int u = __float_as_uint(f);
  u += 0x7FFFu + ((u >> 16) & 1u);  // RNE
  return (unsigned short)(u >> 16);
}

// ---------------- CSR build ----------------
__global__ void k_count(const int* __restrict__ dst, int* __restrict__ cnt, int E) {
  int e = blockIdx.x * blockDim.x + threadIdx.x;
  if (e < E) atomicAdd(&cnt[dst[e]], 1);
}

__global__ void k_dinv(const int* __restrict__ cnt, float* __restrict__ dinv, int n) {
  int i = blockIdx.x * blockDim.x + threadIdx.x;
  if (i < n) dinv[i] = rsqrtf((float)cnt[i] + 1.0f);
}

__global__ void k_alloc(const int* __restrict__ cnt, int* __restrict__ start,
                        int* __restrict__ cursor, int* __restrict__ total, int n) {
  int i = blockIdx.x * blockDim.x + threadIdx.x;
  if (i < n) {
    int c = cnt[i];
    int p = atomicAdd(total, c);
    start[i] = p;
    cursor[i] = p;
  }
}

__global__ void k_place(const int* __restrict__ src, const int* __restrict__ dst,
                        const float* __restrict__ dinv, int* __restrict__ cursor,
                        int2* __restrict__ elist, int E) {
  int e = blockIdx.x * blockDim.x + threadIdx.x;
  if (e >= E) return;
  int s = src[e], d = dst[e];
  int pos = atomicAdd(&cursor[d], 1);
  int2 v;
  v.x = s;
  v.y = __float_as_int(dinv[s] * dinv[d]);
  elist[pos] = v;
}

// ---------------- input conversions for MFMA ----------------
// layer-0 x: [n,30] f32 -> [n,32] bf16 (cols 30,31 zero)
__global__ void k_xcvt(const float* __restrict__ x, unsigned short* __restrict__ xb, int n) {
  int t = blockIdx.x * blockDim.x + threadIdx.x;
  if (t >= n * 32) return;
  int row = t >> 5, c = t & 31;
  float v = (c < 30) ? x[row * 30 + c] : 0.f;
  xb[t] = f2bf(v);
}

// W [K,128] f32 -> Wt [128,Kp] bf16 (transposed, K..Kp-1 zero-padded)
__global__ void k_wcvt(const float* __restrict__ W, unsigned short* __restrict__ Wt,
                       int K, int Kp) {
  int t = blockIdx.x * blockDim.x + threadIdx.x;
  if (t >= 128 * Kp) return;
  int nn = t / Kp, k = t - nn * Kp;
  Wt[t] = f2bf(k < K ? W[k * 128 + nn] : 0.f);
}

// ---------------- MFMA GEMM: C[n,128](bf16) = A[n,Kp](bf16) @ Wt^T ----------------
// block 256 = 4 waves; wave computes 32 rows x 128 cols.
__global__ void k_gemm_mfma(const unsigned short* __restrict__ A,
                            const unsigned short* __restrict__ Wt,
                            unsigned short* __restrict__ C, int n, int Kp) {
  int wave = threadIdx.x >> 6;
  int lane = threadIdx.x & 63;
  int m0 = blockIdx.x * 128 + wave * 32;
  if (m0 >= n) return;
  int lm = lane & 15;   // A row-in-tile / B,C col-in-tile
  int lq = lane >> 4;   // quad -> k offset lq*8 (A,B), row offset lq*4 (C)

  f32x4 acc[2][8] = {};
  const unsigned short* Arow0 = A + (size_t)(m0 + lm) * Kp + lq * 8;
  const unsigned short* Arow1 = Arow0 + (size_t)16 * Kp;
  const unsigned short* Bbase = Wt + (size_t)lm * Kp + lq * 8;

  for (int k0 = 0; k0 < Kp; k0 += 32) {
    bf16x8 a0 = *(const bf16x8*)(Arow0 + k0);
    bf16x8 a1 = *(const bf16x8*)(Arow1 + k0);
#pragma unroll
    for (int t = 0; t < 8; ++t) {
      bf16x8 b = *(const bf16x8*)(Bbase + (size_t)t * 16 * Kp + k0);
      acc[0][t] = __builtin_amdgcn_mfma_f32_16x16x32_bf16(a0, b, acc[0][t], 0, 0, 0);
      acc[1][t] = __builtin_amdgcn_mfma_f32_16x16x32_bf16(a1, b, acc[1][t], 0, 0, 0);
    }
  }
#pragma unroll
  for (int h = 0; h < 2; ++h) {
    int rbase = m0 + h * 16 + lq * 4;
#pragma unroll
    for (int t = 0; t < 8; ++t) {
      int col = t * 16 + lm;
#pragma unroll
      for (int r = 0; r < 4; ++r) {
        int row = rbase + r;
        if (row < n) C[(size_t)row * 128 + col] = f2bf(acc[h][t][r]);
      }
    }
  }
}

// ---------------- CSR gather (bf16 h, 2 cols/thread, 4-edge unroll) ----------------
__global__ void k_gather(const int2* __restrict__ elist, const int* __restrict__ start,
                         const int* __restrict__ cnt, const float* __restrict__ dinv,
                         const unsigned int* __restrict__ h,  // bf16x2, row stride 64 dwords
                         const float* __restrict__ bias, float* __restrict__ agg, int n) {
  int t   = threadIdx.x & 63;
  int row = blockIdx.x * 4 + (threadIdx.x >> 6);
  if (row >= n) return;
  float di = dinv[row];
  float w0 = di * di;
  float2 bv = ((const float2*)bias)[t];
  unsigned int hv = h[(size_t)row * 64 + t];
  float acc0 = fmaf(bf2f(hv & 0xFFFFu), w0, bv.x);
  float acc1 = fmaf(bf2f(hv >> 16),     w0, bv.y);
  int s0 = start[row], len = cnt[row];
  const int2* ep = elist + s0;
  int j = 0;
  for (; j + 4 <= len; j += 4) {
    int2 e0 = ep[j], e1 = ep[j + 1], e2 = ep[j + 2], e3 = ep[j + 3];
    unsigned int v0 = h[(size_t)e0.x * 64 + t];
    unsigned int v1 = h[(size_t)e1.x * 64 + t];
    unsigned int v2 = h[(size_t)e2.x * 64 + t];
    unsigned int v3 = h[(size_t)e3.x * 64 + t];
    float w0f = __int_as_float(e0.y), w1f = __int_as_float(e1.y);
    float w2f = __int_as_float(e2.y), w3f = __int_as_float(e3.y);
    acc0 = fmaf(bf2f(v0 & 0xFFFFu), w0f, acc0);
    acc1 = fmaf(bf2f(v0 >> 16),     w0f, acc1);
    acc0 = fmaf(bf2f(v1 & 0xFFFFu), w1f, acc0);
    acc1 = fmaf(bf2f(v1 >> 16),     w1f, acc1);
    acc0 = fmaf(bf2f(v2 & 0xFFFFu), w2f, acc0);
    acc1 = fmaf(bf2f(v2 >> 16),     w2f, acc1);
    acc0 = fmaf(bf2f(v3 & 0xFFFFu), w3f, acc0);
    acc1 = fmaf(bf2f(v3 >> 16),     w3f, acc1);
  }
  for (; j < len; ++j) {
    int2 e = ep[j];
    unsigned int v = h[(size_t)e.x * 64 + t];
    float wf = __int_as_float(e.y);
    acc0 = fmaf(bf2f(v & 0xFFFFu), wf, acc0);
    acc1 = fmaf(bf2f(v >> 16),     wf, acc1);
  }
  float2 r; r.x = acc0; r.y = acc1;
  ((float2*)agg)[(size_t)row * 64 + t] = r;
}

// ---------------- BN stats ----------------
__global__ void k_bnstats(const float* __restrict__ a, float* __restrict__ bnsum, int n) {
  int col  = threadIdx.x & 127;
  int half = threadIdx.x >> 7;
  float s = 0.f, s2 = 0.f;
  for (int r = blockIdx.x * 2 + half; r < n; r += gridDim.x * 2) {
    float v = a[(size_t)r * 128 + col];
    s += v; s2 += v * v;
  }
  __shared__ float ls[256], ls2[256];
  ls[threadIdx.x] = s; ls2[threadIdx.x] = s2;
  __syncthreads();
  if (threadIdx.x < 128) {
    atomicAdd(&bnsum[col],       ls[threadIdx.x] + ls[threadIdx.x + 128]);
    atomicAdd(&bnsum[128 + col], ls2[threadIdx.x] + ls2[threadIdx.x + 128]);
  }
}

__global__ void k_bnfinal(const float* __restrict__ bnsum, const float* __restrict__ gamma,
                          const float* __restrict__ beta, float* __restrict__ scsh, int n) {
  int c = threadIdx.x;  // 128
  float invn = 1.0f / (float)n;
  float mu  = bnsum[c] * invn;
  float ex2 = bnsum[128 + c] * invn;
  float var = fmaxf(ex2 - mu * mu, 0.f);
  float sc = gamma[c] * rsqrtf(var + BN_EPS);
  scsh[c] = sc;
  scsh[128 + c] = fmaf(-mu, sc, beta[c]);
}

// ---------------- BN apply + ReLU -> bf16 (next gemm input) ----------------
__global__ void k_bnapply_bf(const float* __restrict__ a, const float* __restrict__ scsh,
                             unsigned short* __restrict__ xb, int n) {
  int idx = blockIdx.x * blockDim.x + threadIdx.x;  // over n*32 float4s
  if (idx >= n * 32) return;
  int q = idx & 31;
  float4 v  = ((const float4*)a)[idx];
  float4 sc = ((const float4*)scsh)[q];
  float4 sh = ((const float4*)(scsh + 128))[q];
  ushort4 o;
  o.x = f2bf(fmaxf(fmaf(v.x, sc.x, sh.x), 0.f));
  o.y = f2bf(fmaxf(fmaf(v.y, sc.y, sh.y), 0.f));
  o.z = f2bf(fmaxf(fmaf(v.z, sc.z, sh.z), 0.f));
  o.w = f2bf(fmaxf(fmaf(v.w, sc.w, sh.w), 0.f));
  ((ushort4*)xb)[idx] = o;
}

// ---------------- graph boundaries ----------------
__global__ void k_gstart(const int* __restrict__ batch, int* __restrict__ gstart, int n, int G) {
  int g = blockIdx.x * blockDim.x + threadIdx.x;
  if (g > G) return;
  int lo = 0, hi = n;
  while (lo < hi) {
    int mid = (lo + hi) >> 1;
    if (batch[mid] < g) lo = mid + 1; else hi = mid;
  }
  gstart[g] = lo;
}

// ---------------- mean pool over raw agg, fusing final BN+ReLU ----------------
__global__ void k_pool(const float* __restrict__ a, const float* __restrict__ scsh,
                       const int* __restrict__ gstart, float* __restrict__ pooled) {
  int g = blockIdx.x, c = threadIdx.x;  // 128 threads
  int s = gstart[g], e = gstart[g + 1];
  float sc = scsh[c], sh = scsh[128 + c];
  float acc = 0.f;
  for (int i = s; i < e; ++i)
    acc += fmaxf(fmaf(a[(size_t)i * 128 + c], sc, sh), 0.f);
  float cntf = (float)(e - s);
  pooled[(size_t)g * 128 + c] = acc / fmaxf(cntf, 1.f);
}

// ---------------- head MLP ----------------
__global__ void k_head(const float* __restrict__ pooled, const float* __restrict__ HW1,
                       const float* __restrict__ Hb1, const float* __restrict__ HW2,
                       const float* __restrict__ Hb2, float* __restrict__ out) {
  int g = blockIdx.x, j = threadIdx.x;  // 64 threads
  __shared__ float p[128];
  p[j]      = pooled[(size_t)g * 128 + j];
  p[j + 64] = pooled[(size_t)g * 128 + 64 + j];
  __syncthreads();
  float acc = Hb1[j];
  for (int k = 0; k < 128; ++k) acc = fmaf(p[k], HW1[k * 64 + j], acc);
  float v = fmaxf(acc, 0.f) * HW2[j];
  for (int off = 32; off > 0; off >>= 1) v += __shfl_down(v, off);
  if (j == 0) out[g] = v + Hb2[0];
}

extern "C" void kernel_launch(void* const* d_in, const int* in_sizes, int n_in,
                              void* d_out, int out_size, void* d_ws, size_t ws_size,
                              hipStream_t stream) {
  const int F_IN = 30, H = 128;
  const float* x   = (const float*)d_in[0];
  const int* eidx  = (const int*)d_in[1];
  const int* batch = (const int*)d_in[2];
  const int N = in_sizes[0] / F_IN;
  const int E = in_sizes[1] / 2;
  const int G = out_size;
  const int* srcp = eidx;
  const int* dstp = eidx + E;
  const float* HW1 = (const float*)d_in[15];
  const float* Hb1 = (const float*)d_in[16];
  const float* HW2 = (const float*)d_in[17];
  const float* Hb2 = (const float*)d_in[18];
  float* outp = (float*)d_out;

  const int Npad = (N + 127) & ~127;  // gemm reads padded rows (garbage ok, not stored)
  size_t nh = (size_t)Npad * H;

  // workspace layout (same footprint as before: bufH+xbf bf16 = old fp32 bufH)
  unsigned short* bufH = (unsigned short*)d_ws;      // Npad*128 bf16 (gemm out h)
  unsigned short* xbf  = bufH + nh;                  // Npad*128 bf16 (gemm in)
  float* bufX = (float*)(xbf + nh);                  // Npad*128 f32 (agg)
  float* dinv = bufX + nh;                           // N
  int*   cnt    = (int*)(dinv + N);
  int*   startv = cnt + N;
  int*   cursor = startv + N;
  int*   total  = cursor + N;                        // 64 pad
  float* bnsum  = (float*)(total + 64);              // 256
  float* scsh   = bnsum + 256;                       // 256
  float* pooled = scsh + 256;                        // G*128
  int*   gstart = (int*)(pooled + (size_t)G * 128);  // G+1
  unsigned short* Wt0 = (unsigned short*)(gstart + G + 64);  // 128*32
  unsigned short* Wt1 = Wt0 + 128 * 32;                      // 128*128
  unsigned short* Wt2 = Wt1 + 128 * 128;                     // 128*128
  int2*  elist  = (int2*)(Wt2 + 128 * 128 + 64);             // E pairs

  // ---- build CSR (reused by all 3 layers) ----
  hipMemsetAsync(cnt, 0, (size_t)N * sizeof(int), stream);
  hipMemsetAsync(total, 0, sizeof(int), stream);
  k_count<<<(E + 255) / 256, 256, 0, stream>>>(dstp, cnt, E);
  k_dinv<<<(N + 255) / 256, 256, 0, stream>>>(cnt, dinv, N);
  k_alloc<<<(N + 255) / 256, 256, 0, stream>>>(cnt, startv, cursor, total, N);
  k_place<<<(E + 255) / 256, 256, 0, stream>>>(srcp, dstp, dinv, cursor, elist, E);

  // ---- weights -> transposed bf16; layer-0 x -> bf16 [N,32] ----
  k_wcvt<<<(128 * 32 + 255) / 256, 256, 0, stream>>>((const float*)d_in[3], Wt0, F_IN, 32);
  k_wcvt<<<(128 * 128 + 255) / 256, 256, 0, stream>>>((const float*)d_in[7], Wt1, H, 128);
  k_wcvt<<<(128 * 128 + 255) / 256, 256, 0, stream>>>((const float*)d_in[11], Wt2, H, 128);
  k_xcvt<<<(N * 32 + 255) / 256, 256, 0, stream>>>(x, xbf, N);

  const unsigned short* Wts[3] = {Wt0, Wt1, Wt2};
  for (int l = 0; l < 3; ++l) {
    const float* b  = (const float*)d_in[4 + l * 4];
    const float* gm = (const float*)d_in[5 + l * 4];
    const float* bt = (const float*)d_in[6 + l * 4];
    int Kp = (l == 0) ? 32 : 128;

    k_gemm_mfma<<<Npad / 128, 256, 0, stream>>>(xbf, Wts[l], bufH, N, Kp);
    k_gather<<<(N + 3) / 4, 256, 0, stream>>>(elist, startv, cnt, dinv,
                                              (const unsigned int*)bufH, b, bufX, N);
    hipMemsetAsync(bnsum, 0, 256 * sizeof(float), stream);
    k_bnstats<<<512, 256, 0, stream>>>(bufX, bnsum, N);
    k_bnfinal<<<1, 128, 0, stream>>>(bnsum, gm, bt, scsh, N);
    if (l < 2)  // last layer's BN+ReLU fused into k_pool
      k_bnapply_bf<<<(N * 32 + 255) / 256, 256, 0, stream>>>(bufX, scsh, xbf, N);
  }

  // pooling (applies layer-2 BN+ReLU) + head
  k_gstart<<<3, 256, 0, stream>>>(batch, gstart, N, G);
  k_pool<<<G, 128, 0, stream>>>(bufX, scsh, gstart, pooled);
  k_head<<<G, 64, 0, stream>>>(pooled, HW1, Hb1, HW2, Hb2, outp);
}